// Round 5
// baseline (265.597 us; speedup 1.0000x reference)
//
#include <hip/hip_runtime.h>

typedef int i32x4 __attribute__((ext_vector_type(4)));

// async 16B global->LDS (wave-uniform LDS base + lane*16; global addr per-lane)
__device__ __forceinline__ void gl_lds16(const signed char* g, signed char* l) {
    __builtin_amdgcn_global_load_lds(
        (const __attribute__((address_space(1))) void*)g,
        (__attribute__((address_space(3))) void*)l, 16, 0, 0);
}

#define XQ_SCALE 2048.0f
#define XQ_DELTA (1.0f / 2048.0f)

// ---------------- ws init (2 absmax words) ----------------
__global__ void init_ws_kernel(unsigned* p) {
    if (threadIdx.x < 2) p[threadIdx.x] = 0u;
}

// ---------------- absmax of w1 (blocks 0-255) and w2 (blocks 256-511) ----------------
__global__ void absmax2_kernel(const float* __restrict__ w1, const float* __restrict__ w2,
                               unsigned* __restrict__ out) {
    const bool second = blockIdx.x >= 256;
    const float* w = second ? w2 : w1;
    const int n4 = second ? (512 * 512 * 9 / 4) : (512 * 256 * 9 / 4);
    unsigned* o = out + (second ? 1 : 0);
    float m = 0.0f;
    for (int i = (blockIdx.x & 255) * 256 + threadIdx.x; i < n4; i += 65536) {
        float4 v = ((const float4*)w)[i];
        m = fmaxf(m, fmaxf(fmaxf(fabsf(v.x), fabsf(v.y)), fmaxf(fabsf(v.z), fabsf(v.w))));
    }
#pragma unroll
    for (int off = 32; off > 0; off >>= 1)
        m = fmaxf(m, __shfl_down(m, off));
    if ((threadIdx.x & 63) == 0)
        atomicMax(o, __float_as_uint(m));
}

// ---------------- fused prep: w-quant (16B/thr), bias, perimeter halos, x transform ----------
// block ranges:
//   [0,288)      w1 quant        73728 thr x 16 cin
//   [288,864)    w2 quant        147456 thr x 16 cin
//   [864,868)    bias quant      1024 thr
//   [868,1332)   x halo          64*116*16 thr (perimeter 16B chunks)
//   [1332,1812)  act halo        64*60*32 thr
//   [1812,5012)  x transform     3200 blocks: 128c x 32hw tiles
__global__ __launch_bounds__(256) void prep_all_kernel(
    const float* __restrict__ x,
    const float* __restrict__ w1, const float* __restrict__ w2,
    const float* __restrict__ b1, const float* __restrict__ b2,
    const unsigned* __restrict__ absbits,
    const float* __restrict__ in_scale, const float* __restrict__ act1_scale,
    signed char* __restrict__ wq1, signed char* __restrict__ wq2,
    float* __restrict__ bq1, float* __restrict__ bq2,
    signed char* __restrict__ xhi, signed char* __restrict__ xlo,
    signed char* __restrict__ act) {
    __shared__ float t[128][33];
    const int blk = blockIdx.x;
    const int tid = threadIdx.x;
    const uint4 z = {0, 0, 0, 0};

    if (blk < 288) {                       // ---- w1 quant
        const int thr = blk * 256 + tid;   // < 73728
        const int n = thr / 144;
        const int chunk = thr - n * 144;
        const int r = chunk >> 4;
        const int cin0 = (chunk & 15) * 16;
        const int kh = r / 3;
        const int kw = r - kh * 3;
        const float inv_s = 127.0f / __uint_as_float(absbits[0]);
        union { signed char c[16]; uint4 u; } pk;
#pragma unroll
        for (int j = 0; j < 16; ++j) {
            const float v = w1[((n * 256 + cin0 + j) * 3 + kh) * 3 + kw];
            float q = rintf(v * inv_s);
            q = fminf(fmaxf(q, -127.0f), 127.0f);
            pk.c[j] = (signed char)(int)q;
        }
        *(uint4*)&wq1[n * 2304 + r * 256 + cin0] = pk.u;
    } else if (blk < 864) {                // ---- w2 quant
        const int thr = (blk - 288) * 256 + tid;   // < 147456
        const int n = thr / 288;
        const int chunk = thr - n * 288;
        const int r = chunk >> 5;
        const int cin0 = (chunk & 31) * 16;
        const int kh = r / 3;
        const int kw = r - kh * 3;
        const float inv_s = 127.0f / __uint_as_float(absbits[1]);
        union { signed char c[16]; uint4 u; } pk;
#pragma unroll
        for (int j = 0; j < 16; ++j) {
            const float v = w2[((n * 512 + cin0 + j) * 3 + kh) * 3 + kw];
            float q = rintf(v * inv_s);
            q = fminf(fmaxf(q, -127.0f), 127.0f);
            pk.c[j] = (signed char)(int)q;
        }
        *(uint4*)&wq2[n * 4608 + r * 512 + cin0] = pk.u;
    } else if (blk < 868) {                // ---- bias quant
        const int idx = (blk - 864) * 256 + tid;
        if (idx < 512) {
            const float s = (*in_scale) * (__uint_as_float(absbits[0]) * (1.0f / 127.0f));
            float q = rintf(b1[idx] / s);
            q = fminf(fmaxf(q, -2147483648.0f), 2147483648.0f);
            bq1[idx] = q * s;
        } else {
            const int j = idx - 512;
            const float s = (*act1_scale) * (__uint_as_float(absbits[1]) * (1.0f / 127.0f));
            float q = rintf(b2[j] / s);
            q = fminf(fmaxf(q, -2147483648.0f), 2147483648.0f);
            bq2[j] = q * s;
        }
    } else if (blk < 1332) {               // ---- x halo (perimeter of 30x30)
        const int thr = (blk - 868) * 256 + tid;   // < 64*116*16 = 118784
        const int b = thr / (116 * 16);
        const int rr = thr - b * (116 * 16);
        const int p = rr >> 4;
        const int ch = rr & 15;
        int h, w;
        if (p < 30)      { h = 0;          w = p; }
        else if (p < 60) { h = 29;         w = p - 30; }
        else if (p < 88) { h = p - 60 + 1; w = 0; }
        else             { h = p - 88 + 1; w = 29; }
        const int off = (b * 900 + h * 30 + w) * 256 + ch * 16;
        *(uint4*)(xhi + off) = z;
        *(uint4*)(xlo + off) = z;
    } else if (blk < 1812) {               // ---- act halo (perimeter of 16x16)
        const int thr = (blk - 1332) * 256 + tid;  // < 64*60*32 = 122880
        const int b = thr / (60 * 32);
        const int rr = thr - b * (60 * 32);
        const int p = rr >> 5;
        const int ch = rr & 31;
        int h, w;
        if (p < 16)      { h = 0;          w = p; }
        else if (p < 32) { h = 15;         w = p - 16; }
        else if (p < 46) { h = p - 32 + 1; w = 0; }
        else             { h = p - 46 + 1; w = 15; }
        const int off = (b * 256 + h * 16 + w) * 512 + ch * 16;
        *(uint4*)(act + off) = z;
    } else {                               // ---- x: NCHW fp32 -> padded NHWC i8 hi/lo
        const int xb = blk - 1812;         // < 3200
        const int hwb = xb % 25;
        const int rest = xb / 25;
        const int cb = rest & 1;
        const int b = rest >> 1;
        const int c0 = cb * 128;
        const int hw0 = hwb * 32;
        // phase 1: load 128c x 32hw tile (coalesced along hw)
#pragma unroll
        for (int ci = 0; ci < 16; ++ci) {
            const int crow = (tid >> 5) + ci * 8;    // 0..127
            const int hw = hw0 + (tid & 31);
            float v = 0.0f;
            if (hw < 784) v = x[(b * 256 + c0 + crow) * 784 + hw];
            t[crow][tid & 31] = v;
        }
        __syncthreads();
        // phase 2: quantize + 16B stores, all 256 threads
        const int hw_l = tid >> 3;
        const int cg = (tid & 7) * 16;
        const int hw = hw0 + hw_l;
        if (hw < 784) {
            union { signed char c[16]; uint4 u; } ph, pl;
#pragma unroll
            for (int j = 0; j < 16; ++j) {
                const float v = t[cg + j][hw_l];
                int q = (int)rintf(v * XQ_SCALE);
                q = max(-16383, min(16383, q));
                ph.c[j] = (signed char)(q >> 7);     // [-128,127]
                pl.c[j] = (signed char)(q & 127);    // [0,127]; q == 128*qh + ql
            }
            const int r = hw / 28;
            const int o = (b * 900 + (r + 1) * 30 + (hw - r * 28) + 1) * 256 + c0 + cg;
            *(uint4*)&xhi[o] = ph.u;
            *(uint4*)&xlo[o] = pl.u;
        }
    }
}

// ---------------- implicit-GEMM conv, i8 MFMA, 64m x 128n block, 4 waves ----------------
// Wave wv: wm=wv&1 (m-half), wn=wv>>1 (n-half); computes 32m x 64n = 2x4 frags of
// mfma_i32_16x16x64_i8 (conv1: 4x4 with lo limb sharing B frags). LDS XOR-swizzled:
// logical 16B slot s of row r at physical slot s^(r&7) -> conflict-free (verified R4).
template<int CIN, int STRIDE, int HP, int HOUT, bool SPLIT, bool FINAL>
__global__ __launch_bounds__(256, 3) void conv_gemm_kernel(
    const signed char* __restrict__ Ahi,
    const signed char* __restrict__ Alo,
    const signed char* __restrict__ Wt,
    const float* __restrict__ bias,
    const unsigned* __restrict__ wabs,
    const float* __restrict__ s_pre,
    const float* __restrict__ s_act,
    signed char* __restrict__ act_out,  // !FINAL: padded NHWC i8 codes [64][16][16][512]
    float* __restrict__ out_final)      // FINAL: NCHW fp32
{
    constexpr int K = 9 * CIN;
    constexpr int HW = HOUT * HOUT;
    constexpr int LOG2CIN = (CIN == 256) ? 8 : 9;
    constexpr int NC = SPLIT ? 8 : 6;    // staging chunks per wave (1KB each)
    constexpr int NACC = SPLIT ? 4 : 2;  // m-frags (hi [+ lo])

    __shared__ __align__(16) signed char As[64 * 128];                 // 8KB
    __shared__ __align__(16) signed char As2[SPLIT ? 64 * 128 : 16];   // 8KB (conv1)
    __shared__ __align__(16) signed char Bs[128 * 128];                // 16KB

    const int tid = threadIdx.x;
    const int lane = tid & 63;
    const int wv = tid >> 6;            // 0..3
    const int wm = wv & 1;
    const int wn = wv >> 1;
    const int quad = lane >> 4;
    const int l16 = lane & 15;
    const int m0 = blockIdx.y * 64;
    const int n0 = blockIdx.x * 128;

    // staging: chunk = 1KB = 8 rows x 128B; lane -> (row lane>>3, physical slot lane&7)
    const int lrow = lane >> 3;
    const int koff = ((lane & 7) ^ lrow) * 16;   // swizzled logical k-offset

    const signed char* srcb[NC];
    signed char* dstp[NC];
    bool isA[NC];
#pragma unroll
    for (int i = 0; i < NC; ++i) {
        const int g = wv * NC + i;
        int atype;   // 0 = A hi, 1 = A lo, 2 = B
        int c;
        if (SPLIT) {
            atype = (g < 8) ? 0 : (g < 16 ? 1 : 2);
            c = (g < 8) ? g : (g < 16 ? g - 8 : g - 16);
        } else {
            atype = (g < 8) ? 0 : 2;
            c = (g < 8) ? g : g - 8;
        }
        if (atype == 2) {
            srcb[i] = Wt + (n0 + c * 8 + lrow) * K + koff;
            dstp[i] = &Bs[c * 1024];
            isA[i] = false;
        } else {
            const int m = m0 + c * 8 + lrow;
            const int b = m / HW;
            const int rem = m - b * HW;
            const int oh = rem / HOUT;
            const int ow = rem - oh * HOUT;
            const int off = ((b * HP + oh * STRIDE) * HP + ow * STRIDE) * CIN + koff;
            srcb[i] = (atype == 0 ? Ahi : Alo) + off;
            dstp[i] = (atype == 0 ? &As[c * 1024] : &As2[c * 1024]);
            isA[i] = true;
        }
    }

    i32x4 acc[NACC][4];
#pragma unroll
    for (int mi = 0; mi < NACC; ++mi)
#pragma unroll
        for (int ni = 0; ni < 4; ++ni)
            acc[mi][ni] = i32x4{0, 0, 0, 0};

    for (int k0 = 0; k0 < K; k0 += 128) {
        const int r9 = k0 >> LOG2CIN;
        const int c0k = k0 & (CIN - 1);
        const int kh = r9 / 3;
        const int kw = r9 - kh * 3;
        const int ashift = (kh * HP + kw) * CIN + c0k;

        __syncthreads();   // previous iter's frag reads done before overwrite
#pragma unroll
        for (int i = 0; i < NC; ++i)
            gl_lds16(srcb[i] + (isA[i] ? ashift : k0), dstp[i]);
        __syncthreads();   // vmcnt drained -> LDS tiles complete

#pragma unroll
        for (int ks = 0; ks < 2; ++ks) {
            i32x4 af[NACC];
            i32x4 bfr[4];
#pragma unroll
            for (int mi = 0; mi < 2; ++mi) {
                const int row = wm * 32 + mi * 16 + l16;
                const int sl = ((ks * 4 + quad) ^ (row & 7)) * 16;
                af[mi] = *(const i32x4*)&As[row * 128 + sl];
                if constexpr (SPLIT)
                    af[mi + 2] = *(const i32x4*)&As2[row * 128 + sl];
            }
#pragma unroll
            for (int ni = 0; ni < 4; ++ni) {
                const int row = wn * 64 + ni * 16 + l16;
                const int sl = ((ks * 4 + quad) ^ (row & 7)) * 16;
                bfr[ni] = *(const i32x4*)&Bs[row * 128 + sl];
            }
#pragma unroll
            for (int mi = 0; mi < 2; ++mi)
#pragma unroll
                for (int ni = 0; ni < 4; ++ni) {
                    acc[mi][ni] = __builtin_amdgcn_mfma_i32_16x16x64_i8(af[mi], bfr[ni], acc[mi][ni], 0, 0, 0);
                    if constexpr (SPLIT)
                        acc[mi + 2][ni] = __builtin_amdgcn_mfma_i32_16x16x64_i8(af[mi + 2], bfr[ni], acc[mi + 2][ni], 0, 0, 0);
                }
        }
    }

    // epilogue: dequant, add quantized bias, act fake-quant
    float alpha = __uint_as_float(*wabs) * (1.0f / 127.0f);
    if (FINAL) alpha *= *s_pre;      // conv2: acc * (s_a1 * s_w2)
    if (SPLIT) alpha *= XQ_DELTA;    // conv1: (128*acc_hi + acc_lo) * (delta * s_w1)
    const float sact = *s_act;

    float bv[4];
#pragma unroll
    for (int ni = 0; ni < 4; ++ni)
        bv[ni] = bias[n0 + wn * 64 + ni * 16 + l16];

#pragma unroll
    for (int mi = 0; mi < 2; ++mi) {
#pragma unroll
        for (int i = 0; i < 4; ++i) {
            const int m = m0 + wm * 32 + mi * 16 + quad * 4 + i;   // D row = quad*4+i
            const int b = m / HW;
            const int rem = m - b * HW;
            const int oh = rem / HOUT;
            const int ow = rem - oh * HOUT;
#pragma unroll
            for (int ni = 0; ni < 4; ++ni) {
                const int col = n0 + wn * 64 + ni * 16 + l16;       // D col = l16
                int tot = acc[mi][ni][i];
                if constexpr (SPLIT) tot = tot * 128 + acc[mi + 2][ni][i];
                const float v = (float)tot * alpha + bv[ni];
                float q = rintf(v / sact);
                q = fminf(fmaxf(q, -128.0f), 127.0f);
                if (FINAL) {
                    out_final[(b * 512 + col) * HW + oh * HOUT + ow] = q * sact;
                } else {
                    act_out[(b * 256 + (oh + 1) * 16 + (ow + 1)) * 512 + col] = (signed char)(int)q;
                }
            }
        }
    }
}

// ---------------- launch ----------------
extern "C" void kernel_launch(void* const* d_in, const int* in_sizes, int n_in,
                              void* d_out, int out_size, void* d_ws, size_t ws_size,
                              hipStream_t stream) {
    const float* x  = (const float*)d_in[0];   // 64x256x28x28
    const float* w1 = (const float*)d_in[1];   // 512x256x3x3
    const float* b1 = (const float*)d_in[2];   // 512
    const float* w2 = (const float*)d_in[3];   // 512x512x3x3
    const float* b2 = (const float*)d_in[4];   // 512
    const float* in_scale   = (const float*)d_in[5];
    const float* act1_scale = (const float*)d_in[6];
    const float* act2_scale = (const float*)d_in[7];
    float* out = (float*)d_out;                // 64x512x14x14 NCHW fp32

    char* ws = (char*)d_ws;
    unsigned* absbits = (unsigned*)(ws + 0);
    float* bq1 = (float*)(ws + 64);
    float* bq2 = (float*)(ws + 2112);
    signed char* wq1 = (signed char*)(ws + 8192);       // 512*2304 = 1,179,648
    signed char* wq2 = (signed char*)(ws + 1187840);    // 512*4608 = 2,359,296
    signed char* xhi = (signed char*)(ws + 3547136);    // 64*900*256 = 14,745,600
    signed char* xlo = (signed char*)(ws + 18292736);   // 14,745,600
    signed char* act = (signed char*)(ws + 33038336);   // 64*256*512 = 8,388,608 -> ends 41,426,944

    init_ws_kernel<<<1, 64, 0, stream>>>(absbits);
    absmax2_kernel<<<512, 256, 0, stream>>>(w1, w2, absbits);

    // fused: w1/w2 quant + bias quant + perimeter halos + x transform
    prep_all_kernel<<<5012, 256, 0, stream>>>(
        x, w1, w2, b1, b2, absbits, in_scale, act1_scale,
        wq1, wq2, bq1, bq2, xhi, xlo, act);

    // conv1: 256->512, s2, padded 30x30 in, hi/lo i8 limbs, padded act codes out
    conv_gemm_kernel<256, 2, 30, 14, true, false><<<dim3(4, 196), 256, 0, stream>>>(
        xhi, xlo, wq1, bq1, absbits, act1_scale, act1_scale, act, nullptr);

    // conv2: 512->512, s1, padded 16x16 in (exact i8 codes), fp32 NCHW out
    conv_gemm_kernel<512, 1, 16, 14, false, true><<<dim3(4, 196), 256, 0, stream>>>(
        act, nullptr, wq2, bq2, absbits + 1, act1_scale, act2_scale, nullptr, out);
}

// Round 6
// 263.677 us; speedup vs baseline: 1.0073x; 1.0073x over previous
//
#include <hip/hip_runtime.h>

typedef int i32x4 __attribute__((ext_vector_type(4)));

// async 16B global->LDS (wave-uniform LDS base; HW scatters lane*16)
__device__ __forceinline__ void gl_lds16(const signed char* g, signed char* l) {
    __builtin_amdgcn_global_load_lds(
        (const __attribute__((address_space(1))) void*)g,
        (__attribute__((address_space(3))) void*)l, 16, 0, 0);
}

#define XQ_SCALE 2048.0f
#define XQ_DELTA (1.0f / 2048.0f)

// ---------------- ws init (2 absmax words) ----------------
__global__ void init_ws_kernel(unsigned* p) {
    if (threadIdx.x < 2) p[threadIdx.x] = 0u;
}

// ---------------- absmax of w1 (blocks 0-255) and w2 (blocks 256-511) ----------------
__global__ void absmax2_kernel(const float* __restrict__ w1, const float* __restrict__ w2,
                               unsigned* __restrict__ out) {
    const bool second = blockIdx.x >= 256;
    const float* w = second ? w2 : w1;
    const int n4 = second ? (512 * 512 * 9 / 4) : (512 * 256 * 9 / 4);
    unsigned* o = out + (second ? 1 : 0);
    float m = 0.0f;
    for (int i = (blockIdx.x & 255) * 256 + threadIdx.x; i < n4; i += 65536) {
        float4 v = ((const float4*)w)[i];
        m = fmaxf(m, fmaxf(fmaxf(fabsf(v.x), fabsf(v.y)), fmaxf(fabsf(v.z), fabsf(v.w))));
    }
#pragma unroll
    for (int off = 32; off > 0; off >>= 1)
        m = fmaxf(m, __shfl_down(m, off));
    if ((threadIdx.x & 63) == 0)
        atomicMax(o, __float_as_uint(m));
}

// ---------------- fused prep ----------------
// block ranges:
//   [0,512)          w1 quant+transpose (coalesced reads, LDS transpose)
//   [512,1024)       w2 quant+transpose
//   1024             bias quant
//   [1025,1489)      x halo (perimeter)
//   [1489,1969)      act halo (perimeter)
//   [1969,5169)      x transform: 128c x 32hw tiles
__global__ __launch_bounds__(256) void prep_all_kernel(
    const float* __restrict__ x,
    const float* __restrict__ w1, const float* __restrict__ w2,
    const float* __restrict__ b1, const float* __restrict__ b2,
    const unsigned* __restrict__ absbits,
    const float* __restrict__ in_scale, const float* __restrict__ act1_scale,
    signed char* __restrict__ wq1, signed char* __restrict__ wq2,
    float* __restrict__ bq1, float* __restrict__ bq2,
    signed char* __restrict__ xhi, signed char* __restrict__ xlo,
    signed char* __restrict__ act) {
    __shared__ __align__(16) signed char sw[4608];
    __shared__ float t[128][33];
    const int blk = blockIdx.x;
    const int tid = threadIdx.x;
    const uint4 z = {0, 0, 0, 0};

    if (blk < 512) {                       // ---- w1 quant+transpose, n = blk
        const int n = blk;
        const float inv_s = 127.0f / __uint_as_float(absbits[0]);
#pragma unroll
        for (int rd = 0; rd < 9; ++rd) {
            const int idx = rd * 256 + tid;              // 0..2303, coalesced read
            const float v = w1[n * 2304 + idx];
            float q = rintf(v * inv_s);
            q = fminf(fmaxf(q, -127.0f), 127.0f);
            const int cin = idx / 9;
            const int r = idx - cin * 9;
            sw[r * 256 + cin] = (signed char)(int)q;     // k = r*256+cin
        }
        __syncthreads();
        if (tid < 144) *(uint4*)&wq1[n * 2304 + tid * 16] = *(const uint4*)&sw[tid * 16];
    } else if (blk < 1024) {               // ---- w2 quant+transpose, n = blk-512
        const int n = blk - 512;
        const float inv_s = 127.0f / __uint_as_float(absbits[1]);
#pragma unroll
        for (int rd = 0; rd < 18; ++rd) {
            const int idx = rd * 256 + tid;              // 0..4607
            const float v = w2[n * 4608 + idx];
            float q = rintf(v * inv_s);
            q = fminf(fmaxf(q, -127.0f), 127.0f);
            const int cin = idx / 9;
            const int r = idx - cin * 9;
            sw[r * 512 + cin] = (signed char)(int)q;     // k = r*512+cin
        }
        __syncthreads();
        for (int o = tid; o < 288; o += 256)
            *(uint4*)&wq2[n * 4608 + o * 16] = *(const uint4*)&sw[o * 16];
    } else if (blk == 1024) {              // ---- bias quant
        for (int idx = tid; idx < 1024; idx += 256) {
            if (idx < 512) {
                const float s = (*in_scale) * (__uint_as_float(absbits[0]) * (1.0f / 127.0f));
                float q = rintf(b1[idx] / s);
                q = fminf(fmaxf(q, -2147483648.0f), 2147483648.0f);
                bq1[idx] = q * s;
            } else {
                const int j = idx - 512;
                const float s = (*act1_scale) * (__uint_as_float(absbits[1]) * (1.0f / 127.0f));
                float q = rintf(b2[j] / s);
                q = fminf(fmaxf(q, -2147483648.0f), 2147483648.0f);
                bq2[j] = q * s;
            }
        }
    } else if (blk < 1489) {               // ---- x halo (perimeter of 30x30)
        const int thr = (blk - 1025) * 256 + tid;   // < 64*116*16 = 118784
        const int b = thr / (116 * 16);
        const int rr = thr - b * (116 * 16);
        const int p = rr >> 4;
        const int ch = rr & 15;
        int h, w;
        if (p < 30)      { h = 0;          w = p; }
        else if (p < 60) { h = 29;         w = p - 30; }
        else if (p < 88) { h = p - 60 + 1; w = 0; }
        else             { h = p - 88 + 1; w = 29; }
        const int off = (b * 900 + h * 30 + w) * 256 + ch * 16;
        *(uint4*)(xhi + off) = z;
        *(uint4*)(xlo + off) = z;
    } else if (blk < 1969) {               // ---- act halo (perimeter of 16x16)
        const int thr = (blk - 1489) * 256 + tid;  // < 64*60*32 = 122880
        const int b = thr / (60 * 32);
        const int rr = thr - b * (60 * 32);
        const int p = rr >> 5;
        const int ch = rr & 31;
        int h, w;
        if (p < 16)      { h = 0;          w = p; }
        else if (p < 32) { h = 15;         w = p - 16; }
        else if (p < 46) { h = p - 32 + 1; w = 0; }
        else             { h = p - 46 + 1; w = 15; }
        const int off = (b * 256 + h * 16 + w) * 512 + ch * 16;
        *(uint4*)(act + off) = z;
    } else {                               // ---- x: NCHW fp32 -> padded NHWC i8 hi/lo
        const int xb = blk - 1969;         // < 3200
        const int hwb = xb % 25;
        const int rest = xb / 25;
        const int cb = rest & 1;
        const int b = rest >> 1;
        const int c0 = cb * 128;
        const int hw0 = hwb * 32;
#pragma unroll
        for (int ci = 0; ci < 16; ++ci) {
            const int crow = (tid >> 5) + ci * 8;    // 0..127
            const int hw = hw0 + (tid & 31);
            float v = 0.0f;
            if (hw < 784) v = x[(b * 256 + c0 + crow) * 784 + hw];
            t[crow][tid & 31] = v;
        }
        __syncthreads();
        const int hw_l = tid >> 3;
        const int cg = (tid & 7) * 16;
        const int hw = hw0 + hw_l;
        if (hw < 784) {
            union { signed char c[16]; uint4 u; } ph, pl;
#pragma unroll
            for (int j = 0; j < 16; ++j) {
                const float v = t[cg + j][hw_l];
                int q = (int)rintf(v * XQ_SCALE);
                q = max(-16383, min(16383, q));
                ph.c[j] = (signed char)(q >> 7);     // [-128,127]
                pl.c[j] = (signed char)(q & 127);    // [0,127]; q == 128*qh + ql
            }
            const int r = hw / 28;
            const int o = (b * 900 + (r + 1) * 30 + (hw - r * 28) + 1) * 256 + c0 + cg;
            *(uint4*)&xhi[o] = ph.u;
            *(uint4*)&xlo[o] = pl.u;
        }
    }
}

// ---------------- implicit-GEMM conv, i8 MFMA, 128m x 128n block, 4 waves, dbuf LDS ----
// Wave (wm,wn) computes 64m x 64n = 4x4 frags of mfma_i32_16x16x64_i8 (conv1: + 4 lo-limb
// m-frags reusing B). BK=64. LDS rows are 64B; logical 16B slot s of row r stored at
// physical slot s^((r>>1)&3) -> conflict-free in 8-lane phases. Double-buffered: stage
// buf p^1 async while computing buf p; ONE barrier per iter (compiler's pre-barrier
// vmcnt/lgkmcnt drain provides the cross-wave staging handshake).
template<int CIN, int STRIDE, int HP, int HOUT, bool SPLIT, bool FINAL>
__global__ __launch_bounds__(256) void conv_gemm_kernel(
    const signed char* __restrict__ Ahi,
    const signed char* __restrict__ Alo,
    const signed char* __restrict__ Wt,
    const float* __restrict__ bias,
    const unsigned* __restrict__ wabs,
    const float* __restrict__ s_pre,
    const float* __restrict__ s_act,
    signed char* __restrict__ act_out,  // !FINAL: padded NHWC i8 codes [64][16][16][512]
    float* __restrict__ out_final)      // FINAL: NCHW fp32
{
    constexpr int K = 9 * CIN;
    constexpr int HW = HOUT * HOUT;
    constexpr int NIT = K / 64;
    constexpr int NC = SPLIT ? 6 : 4;          // 1KB staging chunks per wave
    constexpr int NACC = SPLIT ? 8 : 4;
    constexpr int BUFSZ = SPLIT ? 24576 : 16384;
    constexpr int BSOFF = SPLIT ? 16384 : 8192;   // Bs region offset; As2 at 8192 (conv1)

    __shared__ __align__(16) signed char smem[2][BUFSZ];

    const int tid = threadIdx.x;
    const int lane = tid & 63;
    const int wv = tid >> 6;            // 0..3
    const int wm = wv & 1;
    const int wn = wv >> 1;
    const int quad = lane >> 4;
    const int l16 = lane & 15;
    const int m0 = blockIdx.y * 128;
    const int n0 = blockIdx.x * 128;

    // staging: chunk = 1KB = 16 rows x 64B; lane -> row lane>>2, phys slot lane&3.
    // global side fetches logical slot (lane&3)^((row>>1)&3).
    const int lrow = lane >> 2;
    const int lslot = lane & 3;

    const signed char* srcb[NC];
    int dsto[NC];
    bool isA[NC];
#pragma unroll
    for (int i = 0; i < NC; ++i) {
        const int g = wv * NC + i;
        int type, c;   // 0 = A hi, 1 = A lo, 2 = B
        if (SPLIT) {
            type = (g < 8) ? 0 : (g < 16 ? 1 : 2);
            c = (g < 8) ? g : (g < 16 ? g - 8 : g - 16);
        } else {
            type = (g < 8) ? 0 : 2;
            c = (g < 8) ? g : g - 8;
        }
        const int r = c * 16 + lrow;                    // row in 128-row tile
        const int koff = (lslot ^ ((r >> 1) & 3)) * 16; // swizzled logical k-offset
        if (type == 2) {
            srcb[i] = Wt + (n0 + r) * K + koff;
            dsto[i] = BSOFF + c * 1024;
            isA[i] = false;
        } else {
            const int m = m0 + r;
            const int b = m / HW;
            const int rem = m - b * HW;
            const int oh = rem / HOUT;
            const int ow = rem - oh * HOUT;
            const int off = ((b * HP + oh * STRIDE) * HP + ow * STRIDE) * CIN + koff;
            srcb[i] = (type == 0 ? Ahi : Alo) + off;
            dsto[i] = (type == 0 ? 0 : 8192) + c * 1024;
            isA[i] = true;
        }
    }

    i32x4 acc[NACC][4];
#pragma unroll
    for (int mi = 0; mi < NACC; ++mi)
#pragma unroll
        for (int ni = 0; ni < 4; ++ni)
            acc[mi][ni] = i32x4{0, 0, 0, 0};

    // prologue: stage iter 0 into buf 0
    {
        constexpr int ashift0 = 0;
#pragma unroll
        for (int i = 0; i < NC; ++i)
            gl_lds16(srcb[i] + (isA[i] ? ashift0 : 0), &smem[0][dsto[i]]);
    }

    int p = 0;
    for (int it = 0; it < NIT; ++it) {
        __syncthreads();   // drains vmcnt (my stage) + lgkmcnt; all waves' buf[p] ready,
                           // all waves done reading buf[p^1] from previous iter
        if (it + 1 < NIT) {
            const int k0 = (it + 1) * 64;
            const int r9 = k0 / CIN;
            const int kh = r9 / 3;
            const int kw = r9 - kh * 3;
            const int ashift = (kh * HP + kw) * CIN + (k0 & (CIN - 1));
            const int q2 = p ^ 1;
#pragma unroll
            for (int i = 0; i < NC; ++i)
                gl_lds16(srcb[i] + (isA[i] ? ashift : k0), &smem[q2][dsto[i]]);
        }

        // compute from buf p
        i32x4 af[NACC];
        i32x4 bfr[4];
#pragma unroll
        for (int mi = 0; mi < 4; ++mi) {
            const int row = wm * 64 + mi * 16 + l16;
            const int sl = (quad ^ ((row >> 1) & 3)) * 16;
            af[mi] = *(const i32x4*)&smem[p][row * 64 + sl];
            if constexpr (SPLIT)
                af[mi + 4] = *(const i32x4*)&smem[p][8192 + row * 64 + sl];
        }
#pragma unroll
        for (int ni = 0; ni < 4; ++ni) {
            const int row = wn * 64 + ni * 16 + l16;
            const int sl = (quad ^ ((row >> 1) & 3)) * 16;
            bfr[ni] = *(const i32x4*)&smem[p][BSOFF + row * 64 + sl];
        }
#pragma unroll
        for (int mi = 0; mi < 4; ++mi)
#pragma unroll
            for (int ni = 0; ni < 4; ++ni) {
                acc[mi][ni] = __builtin_amdgcn_mfma_i32_16x16x64_i8(af[mi], bfr[ni], acc[mi][ni], 0, 0, 0);
                if constexpr (SPLIT)
                    acc[mi + 4][ni] = __builtin_amdgcn_mfma_i32_16x16x64_i8(af[mi + 4], bfr[ni], acc[mi + 4][ni], 0, 0, 0);
            }
        p ^= 1;
    }

    // epilogue: dequant, add quantized bias, act fake-quant
    float alpha = __uint_as_float(*wabs) * (1.0f / 127.0f);
    if (FINAL) alpha *= *s_pre;      // conv2: acc * (s_a1 * s_w2)
    if (SPLIT) alpha *= XQ_DELTA;    // conv1: (128*acc_hi + acc_lo) * (delta * s_w1)
    const float sact = *s_act;

    float bv[4];
#pragma unroll
    for (int ni = 0; ni < 4; ++ni)
        bv[ni] = bias[n0 + wn * 64 + ni * 16 + l16];

#pragma unroll
    for (int mi = 0; mi < 4; ++mi) {
#pragma unroll
        for (int i = 0; i < 4; ++i) {
            const int m = m0 + wm * 64 + mi * 16 + quad * 4 + i;   // D row = quad*4+i
            const int b = m / HW;
            const int rem = m - b * HW;
            const int oh = rem / HOUT;
            const int ow = rem - oh * HOUT;
#pragma unroll
            for (int ni = 0; ni < 4; ++ni) {
                const int col = n0 + wn * 64 + ni * 16 + l16;       // D col = l16
                int tot = acc[mi][ni][i];
                if constexpr (SPLIT) tot = tot * 128 + acc[mi + 4][ni][i];
                const float v = (float)tot * alpha + bv[ni];
                float q = rintf(v / sact);
                q = fminf(fmaxf(q, -128.0f), 127.0f);
                if (FINAL) {
                    out_final[(b * 512 + col) * HW + oh * HOUT + ow] = q * sact;
                } else {
                    act_out[(b * 256 + (oh + 1) * 16 + (ow + 1)) * 512 + col] = (signed char)(int)q;
                }
            }
        }
    }
}

// ---------------- launch ----------------
extern "C" void kernel_launch(void* const* d_in, const int* in_sizes, int n_in,
                              void* d_out, int out_size, void* d_ws, size_t ws_size,
                              hipStream_t stream) {
    const float* x  = (const float*)d_in[0];   // 64x256x28x28
    const float* w1 = (const float*)d_in[1];   // 512x256x3x3
    const float* b1 = (const float*)d_in[2];   // 512
    const float* w2 = (const float*)d_in[3];   // 512x512x3x3
    const float* b2 = (const float*)d_in[4];   // 512
    const float* in_scale   = (const float*)d_in[5];
    const float* act1_scale = (const float*)d_in[6];
    const float* act2_scale = (const float*)d_in[7];
    float* out = (float*)d_out;                // 64x512x14x14 NCHW fp32

    char* ws = (char*)d_ws;
    unsigned* absbits = (unsigned*)(ws + 0);
    float* bq1 = (float*)(ws + 64);
    float* bq2 = (float*)(ws + 2112);
    signed char* wq1 = (signed char*)(ws + 8192);       // 512*2304 = 1,179,648
    signed char* wq2 = (signed char*)(ws + 1187840);    // 512*4608 = 2,359,296
    signed char* xhi = (signed char*)(ws + 3547136);    // 64*900*256 = 14,745,600
    signed char* xlo = (signed char*)(ws + 18292736);   // 14,745,600
    signed char* act = (signed char*)(ws + 33038336);   // 64*256*512 = 8,388,608 -> ends 41,426,944

    init_ws_kernel<<<1, 64, 0, stream>>>(absbits);
    absmax2_kernel<<<512, 256, 0, stream>>>(w1, w2, absbits);

    // fused: w transpose-quant + bias quant + perimeter halos + x transform
    prep_all_kernel<<<5169, 256, 0, stream>>>(
        x, w1, w2, b1, b2, absbits, in_scale, act1_scale,
        wq1, wq2, bq1, bq2, xhi, xlo, act);

    // conv1: 256->512, s2, padded 30x30 in, hi/lo i8 limbs, padded act codes out
    conv_gemm_kernel<256, 2, 30, 14, true, false><<<dim3(4, 98), 256, 0, stream>>>(
        xhi, xlo, wq1, bq1, absbits, act1_scale, act1_scale, act, nullptr);

    // conv2: 512->512, s1, padded 16x16 in (exact i8 codes), fp32 NCHW out
    conv_gemm_kernel<512, 1, 16, 14, false, true><<<dim3(4, 98), 256, 0, stream>>>(
        act, nullptr, wq2, bq2, absbits + 1, act1_scale, act2_scale, nullptr, out);
}

// Round 7
// 256.204 us; speedup vs baseline: 1.0367x; 1.0292x over previous
//
#include <hip/hip_runtime.h>

typedef int i32x4 __attribute__((ext_vector_type(4)));

// async 16B global->LDS (wave-uniform LDS base; HW scatters lane*16)
__device__ __forceinline__ void gl_lds16(const signed char* g, signed char* l) {
    __builtin_amdgcn_global_load_lds(
        (const __attribute__((address_space(1))) void*)g,
        (__attribute__((address_space(3))) void*)l, 16, 0, 0);
}

#define XQ_SCALE 2048.0f
#define XQ_DELTA (1.0f / 2048.0f)

// ---------------- absmax partials: block b -> part[b]; b<256: w1, else w2 ----------------
// Plain stores (no init, no atomics).
__global__ __launch_bounds__(256) void absmax2_kernel(const float* __restrict__ w1,
                                                      const float* __restrict__ w2,
                                                      float* __restrict__ part) {
    __shared__ float sred[4];
    const bool second = blockIdx.x >= 256;
    const float* w = second ? w2 : w1;
    const int n4 = second ? 589824 : 294912;   // elements/4
    float m = 0.0f;
    for (int i = (blockIdx.x & 255) * 256 + threadIdx.x; i < n4; i += 65536) {
        float4 v = ((const float4*)w)[i];
        m = fmaxf(m, fmaxf(fmaxf(fabsf(v.x), fabsf(v.y)), fmaxf(fabsf(v.z), fabsf(v.w))));
    }
#pragma unroll
    for (int off = 32; off > 0; off >>= 1)
        m = fmaxf(m, __shfl_down(m, off));
    if ((threadIdx.x & 63) == 0) sred[threadIdx.x >> 6] = m;
    __syncthreads();
    if (threadIdx.x == 0)
        part[blockIdx.x] = fmaxf(fmaxf(sred[0], sred[1]), fmaxf(sred[2], sred[3]));
}

// reduce 256 partials to a block-wide max (all 256 threads participate)
__device__ __forceinline__ float block_max256(const float* __restrict__ part, int base,
                                              float* __restrict__ sred) {
    float m = part[base + (threadIdx.x & 255)];
#pragma unroll
    for (int off = 32; off > 0; off >>= 1)
        m = fmaxf(m, __shfl_down(m, off));
    __syncthreads();                 // protect sred from previous use
    if ((threadIdx.x & 63) == 0) sred[threadIdx.x >> 6] = m;
    __syncthreads();
    return fmaxf(fmaxf(sred[0], sred[1]), fmaxf(sred[2], sred[3]));
}

// ---------------- fused prep ----------------
// block ranges:
//   [0,512)          w1 quant+transpose (coalesced reads, LDS transpose)
//   [512,1024)       w2 quant+transpose
//   1024             bias quant + wmax store
//   [1025,1489)      x halo (perimeter)
//   [1489,1969)      act halo (perimeter)
//   [1969,5169)      x transform: 128c x 32hw tiles
__global__ __launch_bounds__(256) void prep_all_kernel(
    const float* __restrict__ x,
    const float* __restrict__ w1, const float* __restrict__ w2,
    const float* __restrict__ b1, const float* __restrict__ b2,
    const float* __restrict__ part,
    const float* __restrict__ in_scale, const float* __restrict__ act1_scale,
    signed char* __restrict__ wq1, signed char* __restrict__ wq2,
    float* __restrict__ bq1, float* __restrict__ bq2,
    float* __restrict__ wmax,
    signed char* __restrict__ xhi, signed char* __restrict__ xlo,
    signed char* __restrict__ act) {
    __shared__ __align__(16) signed char sw[4608];
    __shared__ float t[128][33];
    __shared__ float sred[4];
    const int blk = blockIdx.x;
    const int tid = threadIdx.x;
    const uint4 z = {0, 0, 0, 0};

    if (blk < 512) {                       // ---- w1 quant+transpose, n = blk
        const float inv_s = 127.0f / block_max256(part, 0, sred);
        const int n = blk;
#pragma unroll
        for (int rd = 0; rd < 9; ++rd) {
            const int idx = rd * 256 + tid;              // 0..2303, coalesced read
            const float v = w1[n * 2304 + idx];
            float q = rintf(v * inv_s);
            q = fminf(fmaxf(q, -127.0f), 127.0f);
            const int cin = idx / 9;
            const int r = idx - cin * 9;
            sw[r * 256 + cin] = (signed char)(int)q;     // k = r*256+cin
        }
        __syncthreads();
        if (tid < 144) *(uint4*)&wq1[n * 2304 + tid * 16] = *(const uint4*)&sw[tid * 16];
    } else if (blk < 1024) {               // ---- w2 quant+transpose, n = blk-512
        const float inv_s = 127.0f / block_max256(part, 256, sred);
        const int n = blk - 512;
#pragma unroll
        for (int rd = 0; rd < 18; ++rd) {
            const int idx = rd * 256 + tid;              // 0..4607
            const float v = w2[n * 4608 + idx];
            float q = rintf(v * inv_s);
            q = fminf(fmaxf(q, -127.0f), 127.0f);
            const int cin = idx / 9;
            const int r = idx - cin * 9;
            sw[r * 512 + cin] = (signed char)(int)q;     // k = r*512+cin
        }
        __syncthreads();
        for (int o = tid; o < 288; o += 256)
            *(uint4*)&wq2[n * 4608 + o * 16] = *(const uint4*)&sw[o * 16];
    } else if (blk == 1024) {              // ---- bias quant + wmax store
        const float m1 = block_max256(part, 0, sred);
        const float m2 = block_max256(part, 256, sred);
        if (tid == 0) { wmax[0] = m1; wmax[1] = m2; }
        if (tid < 512) {
            const float s = (*in_scale) * (m1 * (1.0f / 127.0f));
            // tid covers 0..255 only (blockDim 256): loop both halves
        }
        for (int idx = tid; idx < 1024; idx += 256) {
            if (idx < 512) {
                const float s = (*in_scale) * (m1 * (1.0f / 127.0f));
                float q = rintf(b1[idx] / s);
                q = fminf(fmaxf(q, -2147483648.0f), 2147483648.0f);
                bq1[idx] = q * s;
            } else {
                const int j = idx - 512;
                const float s = (*act1_scale) * (m2 * (1.0f / 127.0f));
                float q = rintf(b2[j] / s);
                q = fminf(fmaxf(q, -2147483648.0f), 2147483648.0f);
                bq2[j] = q * s;
            }
        }
    } else if (blk < 1489) {               // ---- x halo (perimeter of 30x30)
        const int thr = (blk - 1025) * 256 + tid;   // < 64*116*16 = 118784
        const int b = thr / (116 * 16);
        const int rr = thr - b * (116 * 16);
        const int p = rr >> 4;
        const int ch = rr & 15;
        int h, w;
        if (p < 30)      { h = 0;          w = p; }
        else if (p < 60) { h = 29;         w = p - 30; }
        else if (p < 88) { h = p - 60 + 1; w = 0; }
        else             { h = p - 88 + 1; w = 29; }
        const int off = (b * 900 + h * 30 + w) * 256 + ch * 16;
        *(uint4*)(xhi + off) = z;
        *(uint4*)(xlo + off) = z;
    } else if (blk < 1969) {               // ---- act halo (perimeter of 16x16)
        const int thr = (blk - 1489) * 256 + tid;  // < 64*60*32 = 122880
        const int b = thr / (60 * 32);
        const int rr = thr - b * (60 * 32);
        const int p = rr >> 5;
        const int ch = rr & 31;
        int h, w;
        if (p < 16)      { h = 0;          w = p; }
        else if (p < 32) { h = 15;         w = p - 16; }
        else if (p < 46) { h = p - 32 + 1; w = 0; }
        else             { h = p - 46 + 1; w = 15; }
        const int off = (b * 256 + h * 16 + w) * 512 + ch * 16;
        *(uint4*)(act + off) = z;
    } else {                               // ---- x: NCHW fp32 -> padded NHWC i8 hi/lo
        const int xb = blk - 1969;         // < 3200
        const int hwb = xb % 25;
        const int rest = xb / 25;
        const int cb = rest & 1;
        const int b = rest >> 1;
        const int c0 = cb * 128;
        const int hw0 = hwb * 32;
#pragma unroll
        for (int ci = 0; ci < 16; ++ci) {
            const int crow = (tid >> 5) + ci * 8;    // 0..127
            const int hw = hw0 + (tid & 31);
            float v = 0.0f;
            if (hw < 784) v = x[(b * 256 + c0 + crow) * 784 + hw];
            t[crow][tid & 31] = v;
        }
        __syncthreads();
        const int hw_l = tid >> 3;
        const int cg = (tid & 7) * 16;
        const int hw = hw0 + hw_l;
        if (hw < 784) {
            union { signed char c[16]; uint4 u; } ph, pl;
#pragma unroll
            for (int j = 0; j < 16; ++j) {
                const float v = t[cg + j][hw_l];
                int q = (int)rintf(v * XQ_SCALE);
                q = max(-16383, min(16383, q));
                ph.c[j] = (signed char)(q >> 7);     // [-128,127]
                pl.c[j] = (signed char)(q & 127);    // [0,127]; q == 128*qh + ql
            }
            const int r = hw / 28;
            const int o = (b * 900 + (r + 1) * 30 + (hw - r * 28) + 1) * 256 + c0 + cg;
            *(uint4*)&xhi[o] = ph.u;
            *(uint4*)&xlo[o] = pl.u;
        }
    }
}

// ---------------- implicit-GEMM conv, i8 MFMA, 64m x 128n block, 2 waves ----------------
// R4 structure (best measured: 58us, conflicts=0) + double-buffered LDS with STATIC buffer
// symbols (K-loop unrolled x2) so all LDS addresses are immediate offsets. Per half-iter:
// barrier -> prefetch next k-tile into other buffer -> compute current buffer. The prefetch
// has the full MFMA window to land before the next barrier's vmcnt(0) drain.
// Wave wv owns n-half wv: 64m x 64n = 4x4 frags of mfma_i32_16x16x64_i8 (conv1: + 4 lo-limb
// m-frags sharing B). BK=128. Swizzle (verified R4/R5): logical 16B slot s of row r stored
// at physical slot s^(r&7).
template<int CIN, int STRIDE, int HP, int HOUT, bool SPLIT, bool FINAL>
__global__ __launch_bounds__(128) void conv_gemm_kernel(
    const signed char* __restrict__ Ahi,
    const signed char* __restrict__ Alo,
    const signed char* __restrict__ Wt,
    const float* __restrict__ bias,
    const float* __restrict__ wmax,
    const float* __restrict__ s_pre,
    const float* __restrict__ s_act,
    signed char* __restrict__ act_out,  // !FINAL: padded NHWC i8 codes [64][16][16][512]
    float* __restrict__ out_final)      // FINAL: NCHW fp32
{
    constexpr int K = 9 * CIN;
    constexpr int HW = HOUT * HOUT;
    constexpr int NIT = K / 128;               // 18 (conv1) / 36 (conv2) — both even
    constexpr int NC = SPLIT ? 16 : 12;        // 1KB staging chunks per wave
    constexpr int NACC = SPLIT ? 8 : 4;
    constexpr int BSOFF = SPLIT ? 16384 : 8192;
    constexpr int BUFSZ = BSOFF + 16384;

    __shared__ __align__(16) signed char sm0[BUFSZ];
    __shared__ __align__(16) signed char sm1[BUFSZ];

    const int tid = threadIdx.x;
    const int lane = tid & 63;
    const int wv = tid >> 6;            // 0..1 (n-half)
    const int quad = lane >> 4;
    const int l16 = lane & 15;
    const int m0 = blockIdx.y * 64;
    const int n0 = blockIdx.x * 128;

    // staging: chunk = 1KB = 8 rows x 128B; lane -> (row lane>>3, phys slot lane&7)
    const int lrow = lane >> 3;
    const int koff = ((lane & 7) ^ lrow) * 16;   // swizzled logical k-offset

    const signed char* srcb[NC];
    int dsto[NC];
    bool isA[NC];
#pragma unroll
    for (int i = 0; i < NC; ++i) {
        const int g = wv * NC + i;
        int type, c;   // 0 = A hi, 1 = A lo, 2 = B
        if (SPLIT) {
            type = (g < 8) ? 0 : (g < 16 ? 1 : 2);
            c = (g < 8) ? g : (g < 16 ? g - 8 : g - 16);
        } else {
            type = (g < 8) ? 0 : 2;
            c = (g < 8) ? g : g - 8;
        }
        const int r = c * 8 + lrow;
        if (type == 2) {
            srcb[i] = Wt + (n0 + r) * K + koff;
            dsto[i] = BSOFF + c * 1024;
            isA[i] = false;
        } else {
            const int m = m0 + r;
            const int b = m / HW;
            const int rem = m - b * HW;
            const int oh = rem / HOUT;
            const int ow = rem - oh * HOUT;
            const int off = ((b * HP + oh * STRIDE) * HP + ow * STRIDE) * CIN + koff;
            srcb[i] = (type == 0 ? Ahi : Alo) + off;
            dsto[i] = (type == 0 ? 0 : 8192) + c * 1024;
            isA[i] = true;
        }
    }

    i32x4 acc[NACC][4];
#pragma unroll
    for (int mi = 0; mi < NACC; ++mi)
#pragma unroll
        for (int ni = 0; ni < 4; ++ni)
            acc[mi][ni] = i32x4{0, 0, 0, 0};

    auto stage = [&](int k0, signed char* buf) {
        const int r9 = k0 / CIN;                 // wave-uniform SALU
        const int kh = r9 / 3;
        const int kw = r9 - kh * 3;
        const int ashift = (kh * HP + kw) * CIN + (k0 & (CIN - 1));
#pragma unroll
        for (int i = 0; i < NC; ++i)
            gl_lds16(srcb[i] + (isA[i] ? ashift : k0), buf + dsto[i]);
    };

    auto compute = [&](const signed char* buf) {
#pragma unroll
        for (int ks = 0; ks < 2; ++ks) {
            i32x4 af[NACC];
            i32x4 bfr[4];
#pragma unroll
            for (int mi = 0; mi < 4; ++mi) {
                const int row = mi * 16 + l16;
                const int sl = ((ks * 4 + quad) ^ (row & 7)) * 16;
                af[mi] = *(const i32x4*)&buf[row * 128 + sl];
                if constexpr (SPLIT)
                    af[mi + 4] = *(const i32x4*)&buf[8192 + row * 128 + sl];
            }
#pragma unroll
            for (int ni = 0; ni < 4; ++ni) {
                const int row = wv * 64 + ni * 16 + l16;
                const int sl = ((ks * 4 + quad) ^ (row & 7)) * 16;
                bfr[ni] = *(const i32x4*)&buf[BSOFF + row * 128 + sl];
            }
#pragma unroll
            for (int mi = 0; mi < 4; ++mi)
#pragma unroll
                for (int ni = 0; ni < 4; ++ni) {
                    acc[mi][ni] = __builtin_amdgcn_mfma_i32_16x16x64_i8(af[mi], bfr[ni], acc[mi][ni], 0, 0, 0);
                    if constexpr (SPLIT)
                        acc[mi + 4][ni] = __builtin_amdgcn_mfma_i32_16x16x64_i8(af[mi + 4], bfr[ni], acc[mi + 4][ni], 0, 0, 0);
                }
        }
    };

    stage(0, sm0);
    for (int it = 0; it < NIT; it += 2) {
        __syncthreads();                   // sm0 staged (all waves), sm1 reads done
        stage((it + 1) * 128, sm1);        // prefetch overlaps compute below
        compute(sm0);
        __syncthreads();                   // sm1 staged, sm0 reads done
        if (it + 2 < NIT) stage((it + 2) * 128, sm0);
        compute(sm1);
    }

    // epilogue: dequant, add quantized bias, act fake-quant
    float alpha = (*wmax) * (1.0f / 127.0f);
    if (FINAL) alpha *= *s_pre;      // conv2: acc * (s_a1 * s_w2)
    if (SPLIT) alpha *= XQ_DELTA;    // conv1: (128*acc_hi + acc_lo) * (delta * s_w1)
    const float sact = *s_act;

    float bv[4];
#pragma unroll
    for (int ni = 0; ni < 4; ++ni)
        bv[ni] = bias[n0 + wv * 64 + ni * 16 + l16];

#pragma unroll
    for (int mi = 0; mi < 4; ++mi) {
#pragma unroll
        for (int i = 0; i < 4; ++i) {
            const int m = m0 + mi * 16 + quad * 4 + i;   // D row = quad*4+i
            const int b = m / HW;
            const int rem = m - b * HW;
            const int oh = rem / HOUT;
            const int ow = rem - oh * HOUT;
#pragma unroll
            for (int ni = 0; ni < 4; ++ni) {
                const int col = n0 + wv * 64 + ni * 16 + l16;       // D col = l16
                int tot = acc[mi][ni][i];
                if constexpr (SPLIT) tot = tot * 128 + acc[mi + 4][ni][i];
                const float v = (float)tot * alpha + bv[ni];
                float q = rintf(v / sact);
                q = fminf(fmaxf(q, -128.0f), 127.0f);
                if (FINAL) {
                    out_final[(b * 512 + col) * HW + oh * HOUT + ow] = q * sact;
                } else {
                    act_out[(b * 256 + (oh + 1) * 16 + (ow + 1)) * 512 + col] = (signed char)(int)q;
                }
            }
        }
    }
}

// ---------------- launch ----------------
extern "C" void kernel_launch(void* const* d_in, const int* in_sizes, int n_in,
                              void* d_out, int out_size, void* d_ws, size_t ws_size,
                              hipStream_t stream) {
    const float* x  = (const float*)d_in[0];   // 64x256x28x28
    const float* w1 = (const float*)d_in[1];   // 512x256x3x3
    const float* b1 = (const float*)d_in[2];   // 512
    const float* w2 = (const float*)d_in[3];   // 512x512x3x3
    const float* b2 = (const float*)d_in[4];   // 512
    const float* in_scale   = (const float*)d_in[5];
    const float* act1_scale = (const float*)d_in[6];
    const float* act2_scale = (const float*)d_in[7];
    float* out = (float*)d_out;                // 64x512x14x14 NCHW fp32

    char* ws = (char*)d_ws;
    float* part = (float*)(ws + 0);                     // 512 floats
    float* wmax = (float*)(ws + 2048);                  // 2 floats
    float* bq1 = (float*)(ws + 2176);                   // 512 f
    float* bq2 = (float*)(ws + 4224);                   // 512 f
    signed char* wq1 = (signed char*)(ws + 8192);       // 512*2304 = 1,179,648
    signed char* wq2 = (signed char*)(ws + 1187840);    // 512*4608 = 2,359,296
    signed char* xhi = (signed char*)(ws + 3547136);    // 64*900*256 = 14,745,600
    signed char* xlo = (signed char*)(ws + 18292736);   // 14,745,600
    signed char* act = (signed char*)(ws + 33038336);   // 64*256*512 = 8,388,608 -> ends 41,426,944

    absmax2_kernel<<<512, 256, 0, stream>>>(w1, w2, part);

    // fused: w transpose-quant + bias quant + wmax + perimeter halos + x transform
    prep_all_kernel<<<5169, 256, 0, stream>>>(
        x, w1, w2, b1, b2, part, in_scale, act1_scale,
        wq1, wq2, bq1, bq2, wmax, xhi, xlo, act);

    // conv1: 256->512, s2, padded 30x30 in, hi/lo i8 limbs, padded act codes out
    conv_gemm_kernel<256, 2, 30, 14, true, false><<<dim3(4, 196), 128, 0, stream>>>(
        xhi, xlo, wq1, bq1, wmax, act1_scale, act1_scale, act, nullptr);

    // conv2: 512->512, s1, padded 16x16 in (exact i8 codes), fp32 NCHW out
    conv_gemm_kernel<512, 1, 16, 14, false, true><<<dim3(4, 196), 128, 0, stream>>>(
        act, nullptr, wq2, bq2, wmax + 1, act1_scale, act2_scale, nullptr, out);
}

// Round 8
// 246.991 us; speedup vs baseline: 1.0753x; 1.0373x over previous
//
#include <hip/hip_runtime.h>

typedef int i32x4 __attribute__((ext_vector_type(4)));

// async 16B global->LDS (wave-uniform LDS base; HW scatters lane*16)
__device__ __forceinline__ void gl_lds16(const signed char* g, signed char* l) {
    __builtin_amdgcn_global_load_lds(
        (const __attribute__((address_space(1))) void*)g,
        (__attribute__((address_space(3))) void*)l, 16, 0, 0);
}

#define XQ_SCALE 2048.0f
#define XQ_DELTA (1.0f / 2048.0f)

// reduce 256 partials to a block-wide max (all 256 threads participate)
__device__ __forceinline__ float block_max256(const float* __restrict__ part, int base,
                                              float* __restrict__ sred) {
    float m = part[base + (threadIdx.x & 255)];
#pragma unroll
    for (int off = 32; off > 0; off >>= 1)
        m = fmaxf(m, __shfl_down(m, off));
    __syncthreads();
    if ((threadIdx.x & 63) == 0) sred[threadIdx.x >> 6] = m;
    __syncthreads();
    return fmaxf(fmaxf(sred[0], sred[1]), fmaxf(sred[2], sred[3]));
}

// ---------------- dispatch 1: absmax partials + halos + x transform ----------------
// block ranges:
//   [0,512)       absmax partials (b<256: w1, else w2) -> part[b]
//   [512,976)     x halo (perimeter of padded 30x30)
//   [976,1456)    act halo (perimeter of padded 16x16)
//   [1456,4656)   x: NCHW fp32 -> int15 hi/lo i8, padded NHWC [64][30][30][256]
__global__ __launch_bounds__(256) void fused_pre_kernel(
    const float* __restrict__ x,
    const float* __restrict__ w1, const float* __restrict__ w2,
    float* __restrict__ part,
    signed char* __restrict__ xhi, signed char* __restrict__ xlo,
    signed char* __restrict__ act) {
    __shared__ float t[128][33];
    __shared__ float sred[4];
    const int blk = blockIdx.x;
    const int tid = threadIdx.x;
    const uint4 z = {0, 0, 0, 0};

    if (blk < 512) {                       // ---- absmax partials
        const bool second = blk >= 256;
        const float* w = second ? w2 : w1;
        const int n4 = second ? 589824 : 294912;   // elements/4
        float m = 0.0f;
        for (int i = (blk & 255) * 256 + tid; i < n4; i += 65536) {
            float4 v = ((const float4*)w)[i];
            m = fmaxf(m, fmaxf(fmaxf(fabsf(v.x), fabsf(v.y)), fmaxf(fabsf(v.z), fabsf(v.w))));
        }
#pragma unroll
        for (int off = 32; off > 0; off >>= 1)
            m = fmaxf(m, __shfl_down(m, off));
        if ((tid & 63) == 0) sred[tid >> 6] = m;
        __syncthreads();
        if (tid == 0)
            part[blk] = fmaxf(fmaxf(sred[0], sred[1]), fmaxf(sred[2], sred[3]));
    } else if (blk < 976) {                // ---- x halo
        const int thr = (blk - 512) * 256 + tid;   // < 64*116*16 = 118784
        const int b = thr / (116 * 16);
        const int rr = thr - b * (116 * 16);
        const int p = rr >> 4;
        const int ch = rr & 15;
        int h, w;
        if (p < 30)      { h = 0;          w = p; }
        else if (p < 60) { h = 29;         w = p - 30; }
        else if (p < 88) { h = p - 60 + 1; w = 0; }
        else             { h = p - 88 + 1; w = 29; }
        const int off = (b * 900 + h * 30 + w) * 256 + ch * 16;
        *(uint4*)(xhi + off) = z;
        *(uint4*)(xlo + off) = z;
    } else if (blk < 1456) {               // ---- act halo
        const int thr = (blk - 976) * 256 + tid;   // < 64*60*32 = 122880
        const int b = thr / (60 * 32);
        const int rr = thr - b * (60 * 32);
        const int p = rr >> 5;
        const int ch = rr & 31;
        int h, w;
        if (p < 16)      { h = 0;          w = p; }
        else if (p < 32) { h = 15;         w = p - 16; }
        else if (p < 46) { h = p - 32 + 1; w = 0; }
        else             { h = p - 46 + 1; w = 15; }
        const int off = (b * 256 + h * 16 + w) * 512 + ch * 16;
        *(uint4*)(act + off) = z;
    } else {                               // ---- x transform (128c x 32hw tile)
        const int xb = blk - 1456;         // < 3200
        const int hwb = xb % 25;
        const int rest = xb / 25;
        const int cb = rest & 1;
        const int b = rest >> 1;
        const int c0 = cb * 128;
        const int hw0 = hwb * 32;
#pragma unroll
        for (int ci = 0; ci < 16; ++ci) {
            const int crow = (tid >> 5) + ci * 8;    // 0..127
            const int hw = hw0 + (tid & 31);
            float v = 0.0f;
            if (hw < 784) v = x[(b * 256 + c0 + crow) * 784 + hw];
            t[crow][tid & 31] = v;
        }
        __syncthreads();
        const int hw_l = tid >> 3;
        const int cg = (tid & 7) * 16;
        const int hw = hw0 + hw_l;
        if (hw < 784) {
            union { signed char c[16]; uint4 u; } ph, pl;
#pragma unroll
            for (int j = 0; j < 16; ++j) {
                const float v = t[cg + j][hw_l];
                int q = (int)rintf(v * XQ_SCALE);
                q = max(-16383, min(16383, q));
                ph.c[j] = (signed char)(q >> 7);     // [-128,127]
                pl.c[j] = (signed char)(q & 127);    // [0,127]; q == 128*qh + ql
            }
            const int r = hw / 28;
            const int o = (b * 900 + (r + 1) * 30 + (hw - r * 28) + 1) * 256 + c0 + cg;
            *(uint4*)&xhi[o] = ph.u;
            *(uint4*)&xlo[o] = pl.u;
        }
    }
}

// ---------------- dispatch 2: weight quant+transpose, bias quant, wmax ----------------
// [0,512) w1 (n = blk); [512,1024) w2 (n = blk-512); 1024: bias + wmax
__global__ __launch_bounds__(256) void prep_w_kernel(
    const float* __restrict__ w1, const float* __restrict__ w2,
    const float* __restrict__ b1, const float* __restrict__ b2,
    const float* __restrict__ part,
    const float* __restrict__ in_scale, const float* __restrict__ act1_scale,
    signed char* __restrict__ wq1, signed char* __restrict__ wq2,
    float* __restrict__ bq1, float* __restrict__ bq2,
    float* __restrict__ wmax) {
    __shared__ __align__(16) signed char sw[4608];
    __shared__ float sred[4];
    const int blk = blockIdx.x;
    const int tid = threadIdx.x;

    if (blk < 512) {                       // ---- w1 quant+transpose
        const float inv_s = 127.0f / block_max256(part, 0, sred);
        const int n = blk;
#pragma unroll
        for (int rd = 0; rd < 9; ++rd) {
            const int idx = rd * 256 + tid;              // 0..2303, coalesced read
            const float v = w1[n * 2304 + idx];
            float q = rintf(v * inv_s);
            q = fminf(fmaxf(q, -127.0f), 127.0f);
            const int cin = idx / 9;
            const int r = idx - cin * 9;
            sw[r * 256 + cin] = (signed char)(int)q;     // k = r*256+cin
        }
        __syncthreads();
        if (tid < 144) *(uint4*)&wq1[n * 2304 + tid * 16] = *(const uint4*)&sw[tid * 16];
    } else if (blk < 1024) {               // ---- w2 quant+transpose
        const float inv_s = 127.0f / block_max256(part, 256, sred);
        const int n = blk - 512;
#pragma unroll
        for (int rd = 0; rd < 18; ++rd) {
            const int idx = rd * 256 + tid;              // 0..4607
            const float v = w2[n * 4608 + idx];
            float q = rintf(v * inv_s);
            q = fminf(fmaxf(q, -127.0f), 127.0f);
            const int cin = idx / 9;
            const int r = idx - cin * 9;
            sw[r * 512 + cin] = (signed char)(int)q;     // k = r*512+cin
        }
        __syncthreads();
        for (int o = tid; o < 288; o += 256)
            *(uint4*)&wq2[n * 4608 + o * 16] = *(const uint4*)&sw[o * 16];
    } else {                               // ---- bias quant + wmax
        const float m1 = block_max256(part, 0, sred);
        const float m2 = block_max256(part, 256, sred);
        if (tid == 0) { wmax[0] = m1; wmax[1] = m2; }
        for (int idx = tid; idx < 1024; idx += 256) {
            if (idx < 512) {
                const float s = (*in_scale) * (m1 * (1.0f / 127.0f));
                float q = rintf(b1[idx] / s);
                q = fminf(fmaxf(q, -2147483648.0f), 2147483648.0f);
                bq1[idx] = q * s;
            } else {
                const int j = idx - 512;
                const float s = (*act1_scale) * (m2 * (1.0f / 127.0f));
                float q = rintf(b2[j] / s);
                q = fminf(fmaxf(q, -2147483648.0f), 2147483648.0f);
                bq2[j] = q * s;
            }
        }
    }
}

// ---------------- implicit-GEMM conv, i8 MFMA, 64m x 128n block, 4 waves (2 pairs) ------
// R4's proven per-wave structure (64m x 64n tile, BK=128, swizzled LDS, 2 barriers/window)
// at 2x wave concurrency via pair-split:
//   conv1 (SPLIT):  pair 0 = hi-limb GEMM, pair 1 = lo-limb GEMM over FULL K, sharing one
//                   staged buffer set (As-hi 8K | As-lo 8K | Bs 16K = 32KB). All 4 waves
//                   stage 8 chunks each. Combine: tot = 128*acc_hi + acc_lo.
//   conv2 (!SPLIT): pair p computes K-half p; own buffer set (As 8K | Bs 16K) -> 48KB.
//                   Pair's 2 waves stage 12 chunks each. Combine: tot = acc_p0 + acc_p1.
// Pair 1 dumps accs to LDS (reusing staging space) and exits; pair 0 combines + epilogue.
// Swizzle (verified conflict-free R4/R5): logical 16B slot s of row r at phys slot s^(r&7).
template<int CIN, int STRIDE, int HP, int HOUT, bool SPLIT, bool FINAL>
__global__ __launch_bounds__(256, 3) void conv_gemm_kernel(
    const signed char* __restrict__ Ahi,
    const signed char* __restrict__ Alo,
    const signed char* __restrict__ Wt,
    const float* __restrict__ bias,
    const float* __restrict__ wmax,
    const float* __restrict__ s_pre,
    const float* __restrict__ s_act,
    signed char* __restrict__ act_out,  // !FINAL: padded NHWC i8 codes [64][16][16][512]
    float* __restrict__ out_final)      // FINAL: NCHW fp32
{
    constexpr int K = 9 * CIN;
    constexpr int HW = HOUT * HOUT;
    constexpr int NIT = SPLIT ? (K / 128) : (K / 256);   // windows: 18 both
    constexpr int NC = SPLIT ? 8 : 12;                   // staging chunks per wave
    constexpr int LDSZ = SPLIT ? 32768 : 49152;

    __shared__ __align__(16) signed char smem[LDSZ];

    const int tid = threadIdx.x;
    const int lane = tid & 63;
    const int wv = tid >> 6;            // 0..3
    const int pair = wv >> 1;
    const int nh = wv & 1;              // n-half within pair
    const int quad = lane >> 4;
    const int l16 = lane & 15;
    const int m0 = blockIdx.y * 64;
    const int n0 = blockIdx.x * 128;

    // staging: chunk = 1KB = 8 rows x 128B; lane -> (row lane>>3, phys slot lane&7)
    const int lrow = lane >> 3;
    const int koff = ((lane & 7) ^ lrow) * 16;   // swizzled logical k-offset

    const int kbase = SPLIT ? 0 : pair * (K / 2);

    const signed char* srcb[NC];
    int dsto[NC];
    bool isA[NC];
    if constexpr (SPLIT) {
#pragma unroll
        for (int i = 0; i < NC; ++i) {
            const int g = wv * 8 + i;
            const int type = g >> 3;        // 0=A-hi (wave0), 1=A-lo (wave1), 2,3=B
            if (type >= 2) {
                const int c = g - 16;
                srcb[i] = Wt + (n0 + c * 8 + lrow) * K + koff;
                dsto[i] = 16384 + c * 1024;
                isA[i] = false;
            } else {
                const int c = g & 7;
                const int m = m0 + c * 8 + lrow;
                const int b = m / HW;
                const int rem = m - b * HW;
                const int oh = rem / HOUT;
                const int ow = rem - oh * HOUT;
                const int off = ((b * HP + oh * STRIDE) * HP + ow * STRIDE) * CIN + koff;
                srcb[i] = (type == 0 ? Ahi : Alo) + off;
                dsto[i] = type * 8192 + c * 1024;
                isA[i] = true;
            }
        }
    } else {
#pragma unroll
        for (int i = 0; i < NC; ++i) {
            const int g = nh * 12 + i;      // 24 chunks per pair
            if (g < 8) {
                const int c = g;
                const int m = m0 + c * 8 + lrow;
                const int b = m / HW;
                const int rem = m - b * HW;
                const int oh = rem / HOUT;
                const int ow = rem - oh * HOUT;
                const int off = ((b * HP + oh * STRIDE) * HP + ow * STRIDE) * CIN + koff;
                srcb[i] = Ahi + off;
                dsto[i] = pair * 24576 + c * 1024;
                isA[i] = true;
            } else {
                const int c = g - 8;
                srcb[i] = Wt + (n0 + c * 8 + lrow) * K + koff;
                dsto[i] = pair * 24576 + 8192 + c * 1024;
                isA[i] = false;
            }
        }
    }

    const int aoff0 = SPLIT ? (pair * 8192) : (pair * 24576);
    const int boff0 = SPLIT ? 16384 : (pair * 24576 + 8192);

    i32x4 acc[4][4];
#pragma unroll
    for (int mi = 0; mi < 4; ++mi)
#pragma unroll
        for (int ni = 0; ni < 4; ++ni)
            acc[mi][ni] = i32x4{0, 0, 0, 0};

    for (int it = 0; it < NIT; ++it) {
        const int k0 = kbase + it * 128;
        const int r9 = k0 / CIN;            // wave-uniform
        const int kh = r9 / 3;
        const int kw = r9 - kh * 3;
        const int ashift = (kh * HP + kw) * CIN + (k0 & (CIN - 1));

        __syncthreads();                    // previous window's frag reads done
#pragma unroll
        for (int i = 0; i < NC; ++i)
            gl_lds16(srcb[i] + (isA[i] ? ashift : k0), &smem[dsto[i]]);
        __syncthreads();                    // per-wave vmcnt drained; tiles complete

#pragma unroll
        for (int ks = 0; ks < 2; ++ks) {
            i32x4 af[4], bfr[4];
#pragma unroll
            for (int mi = 0; mi < 4; ++mi) {
                const int row = mi * 16 + l16;
                const int sl = ((ks * 4 + quad) ^ (row & 7)) * 16;
                af[mi] = *(const i32x4*)&smem[aoff0 + row * 128 + sl];
            }
#pragma unroll
            for (int ni = 0; ni < 4; ++ni) {
                const int row = nh * 64 + ni * 16 + l16;
                const int sl = ((ks * 4 + quad) ^ (row & 7)) * 16;
                bfr[ni] = *(const i32x4*)&smem[boff0 + row * 128 + sl];
            }
#pragma unroll
            for (int mi = 0; mi < 4; ++mi)
#pragma unroll
                for (int ni = 0; ni < 4; ++ni)
                    acc[mi][ni] = __builtin_amdgcn_mfma_i32_16x16x64_i8(af[mi], bfr[ni], acc[mi][ni], 0, 0, 0);
        }
    }

    // ---- pair combine through LDS (reuse staging space) ----
    __syncthreads();
    if (pair == 1) {
#pragma unroll
        for (int mi = 0; mi < 4; ++mi)
#pragma unroll
            for (int ni = 0; ni < 4; ++ni)
                *(i32x4*)&smem[nh * 16384 + (mi * 4 + ni) * 1024 + lane * 16] = acc[mi][ni];
    }
    __syncthreads();
    if (pair == 1) return;

#pragma unroll
    for (int mi = 0; mi < 4; ++mi)
#pragma unroll
        for (int ni = 0; ni < 4; ++ni) {
            const i32x4 other = *(const i32x4*)&smem[nh * 16384 + (mi * 4 + ni) * 1024 + lane * 16];
            if constexpr (SPLIT)
                acc[mi][ni] = acc[mi][ni] * 128 + other;   // 128*hi + lo
            else
                acc[mi][ni] = acc[mi][ni] + other;         // K-half sum
        }

    // ---- epilogue: dequant, add quantized bias, act fake-quant (pair 0 only) ----
    float alpha = (*wmax) * (1.0f / 127.0f);
    if (FINAL) alpha *= *s_pre;      // conv2: acc * (s_a1 * s_w2)
    if (SPLIT) alpha *= XQ_DELTA;    // conv1: fixed-point dequant
    const float sact = *s_act;

    float bv[4];
#pragma unroll
    for (int ni = 0; ni < 4; ++ni)
        bv[ni] = bias[n0 + nh * 64 + ni * 16 + l16];

#pragma unroll
    for (int mi = 0; mi < 4; ++mi) {
#pragma unroll
        for (int i = 0; i < 4; ++i) {
            const int m = m0 + mi * 16 + quad * 4 + i;   // D row = quad*4+i
            const int b = m / HW;
            const int rem = m - b * HW;
            const int oh = rem / HOUT;
            const int ow = rem - oh * HOUT;
#pragma unroll
            for (int ni = 0; ni < 4; ++ni) {
                const int col = n0 + nh * 64 + ni * 16 + l16;   // D col = l16
                const float v = (float)acc[mi][ni][i] * alpha + bv[ni];
                float q = rintf(v / sact);
                q = fminf(fmaxf(q, -128.0f), 127.0f);
                if (FINAL) {
                    out_final[(b * 512 + col) * HW + oh * HOUT + ow] = q * sact;
                } else {
                    act_out[(b * 256 + (oh + 1) * 16 + (ow + 1)) * 512 + col] = (signed char)(int)q;
                }
            }
        }
    }
}

// ---------------- launch ----------------
extern "C" void kernel_launch(void* const* d_in, const int* in_sizes, int n_in,
                              void* d_out, int out_size, void* d_ws, size_t ws_size,
                              hipStream_t stream) {
    const float* x  = (const float*)d_in[0];   // 64x256x28x28
    const float* w1 = (const float*)d_in[1];   // 512x256x3x3
    const float* b1 = (const float*)d_in[2];   // 512
    const float* w2 = (const float*)d_in[3];   // 512x512x3x3
    const float* b2 = (const float*)d_in[4];   // 512
    const float* in_scale   = (const float*)d_in[5];
    const float* act1_scale = (const float*)d_in[6];
    const float* act2_scale = (const float*)d_in[7];
    float* out = (float*)d_out;                // 64x512x14x14 NCHW fp32

    char* ws = (char*)d_ws;
    float* part = (float*)(ws + 0);                     // 512 floats
    float* wmax = (float*)(ws + 2048);                  // 2 floats
    float* bq1 = (float*)(ws + 2176);                   // 512 f
    float* bq2 = (float*)(ws + 4224);                   // 512 f
    signed char* wq1 = (signed char*)(ws + 8192);       // 512*2304 = 1,179,648
    signed char* wq2 = (signed char*)(ws + 1187840);    // 512*4608 = 2,359,296
    signed char* xhi = (signed char*)(ws + 3547136);    // 64*900*256 = 14,745,600
    signed char* xlo = (signed char*)(ws + 18292736);   // 14,745,600
    signed char* act = (signed char*)(ws + 33038336);   // 64*256*512 = 8,388,608 -> ends 41,426,944

    // dispatch 1: absmax partials + halos + x transform (independent work fused)
    fused_pre_kernel<<<4656, 256, 0, stream>>>(x, w1, w2, part, xhi, xlo, act);

    // dispatch 2: weight quant+transpose + bias quant + wmax (depends on partials)
    prep_w_kernel<<<1025, 256, 0, stream>>>(w1, w2, b1, b2, part, in_scale, act1_scale,
                                            wq1, wq2, bq1, bq2, wmax);

    // conv1: 256->512, s2, padded 30x30 in, hi/lo limb pairs, padded act codes out
    conv_gemm_kernel<256, 2, 30, 14, true, false><<<dim3(4, 196), 256, 0, stream>>>(
        xhi, xlo, wq1, bq1, wmax, act1_scale, act1_scale, act, nullptr);

    // conv2: 512->512, s1, padded 16x16 in (exact i8 codes), K-split pairs, fp32 NCHW out
    conv_gemm_kernel<512, 1, 16, 14, false, true><<<dim3(4, 196), 256, 0, stream>>>(
        act, nullptr, wq2, bq2, wmax + 1, act1_scale, act2_scale, nullptr, out);
}